// Round 4
// baseline (947.510 us; speedup 1.0000x reference)
//
#include <hip/hip_runtime.h>
#include <hip/hip_bf16.h>

namespace {

constexpr int TT = 150;

__device__ __forceinline__ float dot4(float4 a, float4 b) {
  return a.x*b.x + a.y*b.y + a.z*b.z + a.w*b.w;
}

// Block = 256 threads = 4 waves. lane=(r,b): r=lane>>2 (16 rows/wave), b=lane&3
// (4 batch elems/block). Wave w owns rows i = 16w+r (60 real rows; wave 3 has 4
// idle lanes). grid=256 blocks -> B=1024. Quad-broadcast amortizes the banded
// basis LDS reads 4x. Two barriers per timestep.
// OUTPUTS ARE FLOAT32 (reference output dtype) — this was the rounds-1..3 bug.
__launch_bounds__(256, 1)
__global__ void acrkn(const float* __restrict__ lob,   // (B,T,60)
                      const float* __restrict__ ovr,   // (B,T,60)
                      const float* __restrict__ actp,  // (B,T,10)
                      const float* __restrict__ im,    // (B,120)
                      const float* __restrict__ icu,   // (B,60)
                      const float* __restrict__ icl,   // (B,60)
                      const float* __restrict__ ics,   // (B,60)
                      const float* __restrict__ tm11,  // (15,60,60)
                      const float* __restrict__ tm12,
                      const float* __restrict__ tm21,
                      const float* __restrict__ tm22,
                      const float* __restrict__ cw,    // (120,15)
                      const float* __restrict__ cb,    // (15)
                      const float* __restrict__ w1,    // (10,60)
                      const float* __restrict__ b1,    // (60)
                      const float* __restrict__ w2,    // (60,120)
                      const float* __restrict__ b2,    // (120)
                      const float* __restrict__ ltc,   // (120)
                      float* __restrict__ out)
{
  // Band-compacted bases, float4 over kk: f4 idx = ((mat*7+d)*4+c)*60 + i,
  // element kk holds tm_mat[k=4c+kk][i][j=i+d-3] (0 outside band / k=15).
  __shared__ __align__(16) float m4[26880];   // 107520 B
  __shared__ __align__(16) float w2T[7680];   // [col 0..127][j 0..59] = w2[j][col]
  __shared__ __align__(16) float cwc[2048];   // f4 = c*128+p: p<60 -> col p; 64<=p<124 -> col p-4
  __shared__ __align__(16) float stat[1440];  // [vec 0..4][row 0..71][b], row = state_idx+3
  __shared__ __align__(16) float w1s[600];    // [a][j]
  __shared__ float b1s[64];
  __shared__ float b2s[128];
  __shared__ __align__(16) float hbuf[256];   // [b][j 0..63]
  __shared__ float parts[256];                // [w][b][k 0..15]
  __shared__ float cbs[16];

  const int tid = threadIdx.x;

  // ---------------- one-time LDS staging ----------------
  for (int f4 = tid; f4 < 6720; f4 += 256) {
    int tmp = f4;
    const int i   = tmp % 60; tmp /= 60;
    const int c   = tmp % 4;  tmp /= 4;
    const int d   = tmp % 7;  tmp /= 7;
    const int mat = tmp;                       // 0..3
    const int j = i + d - 3;
    const float* tp = (mat == 0) ? tm11 : (mat == 1) ? tm12 : (mat == 2) ? tm21 : tm22;
    float v0 = 0.f, v1 = 0.f, v2 = 0.f, v3 = 0.f;
    if (j >= 0 && j < 60) {
      const int k0 = c*4;
      v0 = tp[((k0+0)*60 + i)*60 + j];
      v1 = tp[((k0+1)*60 + i)*60 + j];
      v2 = tp[((k0+2)*60 + i)*60 + j];
      v3 = (k0+3 < 15) ? tp[((k0+3)*60 + i)*60 + j] : 0.f;
    }
    ((float4*)m4)[f4] = make_float4(v0, v1, v2, v3);
  }
  for (int idx = tid; idx < 7680; idx += 256) {
    const int col = idx / 60;
    const int j   = idx - col*60;
    w2T[idx] = (col < 120) ? w2[j*120 + col] : 0.f;
  }
  for (int f4 = tid; f4 < 512; f4 += 256) {
    const int p = f4 & 127, c = f4 >> 7;
    const int col = (p < 60) ? p : ((p >= 64 && p < 124) ? (p - 4) : -1);
    float v0 = 0.f, v1 = 0.f, v2 = 0.f, v3 = 0.f;
    if (col >= 0) {
      const int k0 = c*4;
      v0 = cw[col*15 + k0+0];
      v1 = cw[col*15 + k0+1];
      v2 = cw[col*15 + k0+2];
      v3 = (k0+3 < 15) ? cw[col*15 + k0+3] : 0.f;
    }
    ((float4*)cwc)[f4] = make_float4(v0, v1, v2, v3);
  }
  for (int idx = tid; idx < 1440; idx += 256) stat[idx] = 0.f;
  for (int idx = tid; idx < 600;  idx += 256) w1s[idx] = w1[idx];
  if (tid < 64)  b1s[tid] = (tid < 60)  ? b1[tid] : 0.f;
  if (tid < 128) b2s[tid] = (tid < 120) ? b2[tid] : 0.f;
  if (tid < 16)  cbs[tid] = (tid < 15)  ? cb[tid] : 0.f;

  const int lane = tid & 63;
  const int w = tid >> 6;
  const int r = lane >> 2;
  const int b = lane & 3;
  const int iraw = w*16 + r;
  const bool valid = (iraw < 60);
  const int ii = valid ? iraw : 0;
  const int gb = blockIdx.x*4 + b;

  // carry registers (prior state entering step t)
  float mu_c = 0.f, ml_c = 0.f, cu_c = 1.f, cl_c = 1.f, cs_c = 0.f;
  float tcu_r = 1.f, tcl_r = 1.f;
  if (valid) {
    mu_c = im[gb*120 + ii];
    ml_c = im[gb*120 + 60 + ii];
    cu_c = icu[gb*60 + ii];
    cl_c = icl[gb*60 + ii];
    cs_c = ics[gb*60 + ii];
    const float l0 = ltc[ii], l1 = ltc[60 + ii];
    tcu_r = (l0 >= 0.f) ? l0 + 1.f : __expf(l0);   // elup1
    tcl_r = (l1 >= 0.f) ? l1 + 1.f : __expf(l1);
  }

  const float4* m4_4 = (const float4*)m4;
  const float4* w2T4 = (const float4*)w2T;
  const float4* cwc4 = (const float4*)cwc;
  const float4* hb4  = (const float4*)hbuf;

  float* o0 = out;                 // post_means  (B,T,120)
  float* o1 = out + 18432000L;     // pcu (B,T,60)
  float* o2 = out + 27648000L;     // pcl
  float* o3 = out + 36864000L;     // pcs
  float* o4 = out + 46080000L;     // prior_means (B,T,120)
  float* o5 = out + 64512000L;     // ncu
  float* o6 = out + 73728000L;     // ncl
  float* o7 = out + 82944000L;     // ncs

  __syncthreads();

  for (int t = 0; t < TT; ++t) {
    // ---- phase A: Kalman update ----
    const long ib = (long)gb*(TT*60) + t*60 + ii;
    float obs = 0.f, ovv = 1.f;
    if (valid) { obs = lob[ib]; ovv = ovr[ib]; }
    const float denom = cu_c + ovv;
    const float inv = 1.0f / denom;
    const float qu = cu_c * inv;
    const float ql = cs_c * inv;
    const float res = obs - mu_c;
    float pm_u = mu_c + qu*res;
    float pm_l = ml_c + ql*res;
    const float f1 = 1.f - qu;
    float pcu = f1*cu_c, pcs = f1*cs_c, pcl = cl_c - ql*cs_c;
    if (!valid) { pm_u = 0.f; pm_l = 0.f; pcu = 0.f; pcs = 0.f; pcl = 0.f; }

    // ---- control MLP hidden unit j = iraw (action via wave-broadcast loads) ----
    float hv = 0.f;
    if (valid) {
      float acc = b1s[ii];
      const long ab = (long)gb*(TT*10) + t*10;
      #pragma unroll
      for (int a = 0; a < 10; ++a) acc += actp[ab + a] * w1s[a*60 + ii];
      hv = fmaxf(acc, 0.f);
    }
    hbuf[b*64 + iraw] = hv;

    // ---- stage posterior state for banded neighbor access ----
    if (valid) {
      stat[(0*72 + ii + 3)*4 + b] = pm_u;
      stat[(1*72 + ii + 3)*4 + b] = pm_l;
      stat[(2*72 + ii + 3)*4 + b] = pcu;
      stat[(3*72 + ii + 3)*4 + b] = pcs;
      stat[(4*72 + ii + 3)*4 + b] = pcl;
    }

    // ---- coeff logit partials: p[k] = pm_u*cw[ii][k] + pm_l*cw[60+ii][k] ----
    float p[16];
    #pragma unroll
    for (int k = 0; k < 16; ++k) p[k] = 0.f;
    #pragma unroll
    for (int c = 0; c < 4; ++c) {
      const float4 wu = cwc4[c*128 + ii];
      const float4 wl = cwc4[c*128 + 64 + ii];
      p[c*4+0] += pm_u*wu.x + pm_l*wl.x;
      p[c*4+1] += pm_u*wu.y + pm_l*wl.y;
      p[c*4+2] += pm_u*wu.z + pm_l*wl.z;
      p[c*4+3] += pm_u*wu.w + pm_l*wl.w;
    }
    // intra-wave allreduce over the 16 r-lanes (masks touch bits 2..5; b preserved)
    #pragma unroll
    for (int m = 4; m <= 32; m <<= 1) {
      #pragma unroll
      for (int k = 0; k < 16; ++k) p[k] += __shfl_xor(p[k], m);
    }
    if (r == 0) {
      #pragma unroll
      for (int k = 0; k < 16; ++k) parts[(w*4 + b)*16 + k] = p[k];
    }
    __syncthreads();   // B1

    // ---- phase C: finalize logits + softmax (redundant per lane, same per b) ----
    float q[16];
    #pragma unroll
    for (int k = 0; k < 16; ++k) q[k] = cbs[k];
    #pragma unroll
    for (int ww = 0; ww < 4; ++ww) {
      #pragma unroll
      for (int k = 0; k < 16; ++k) q[k] += parts[(ww*4 + b)*16 + k];
    }
    float mx = q[0];
    #pragma unroll
    for (int k = 1; k < 15; ++k) mx = fmaxf(mx, q[k]);
    float ce[15];
    float ssum = 0.f;
    #pragma unroll
    for (int k = 0; k < 15; ++k) { ce[k] = __expf(q[k] - mx); ssum += ce[k]; }
    const float rs = 1.f / ssum;
    #pragma unroll
    for (int k = 0; k < 15; ++k) ce[k] *= rs;
    const float4 c0 = make_float4(ce[0],  ce[1],  ce[2],  ce[3]);
    const float4 c1 = make_float4(ce[4],  ce[5],  ce[6],  ce[7]);
    const float4 c2 = make_float4(ce[8],  ce[9],  ce[10], ce[11]);
    const float4 c3 = make_float4(ce[12], ce[13], ce[14], 0.f);

    // ---- ctrl = relu(act@w1+b1)@w2 + b2, cols ii and 60+ii ----
    float4 au = make_float4(0,0,0,0), al = au;
    #pragma unroll
    for (int jc = 0; jc < 15; ++jc) {
      const float4 hj = hb4[b*16 + jc];
      const float4 wu = w2T4[ii*15 + jc];
      const float4 wl = w2T4[(60 + ii)*15 + jc];
      au.x += hj.x*wu.x; au.y += hj.y*wu.y; au.z += hj.z*wu.z; au.w += hj.w*wu.w;
      al.x += hj.x*wl.x; al.y += hj.y*wl.y; al.z += hj.z*wl.z; al.w += hj.w*wl.w;
    }
    const float ctrl_u = b2s[ii]      + (au.x + au.y + au.z + au.w);
    const float ctrl_l = b2s[60 + ii] + (al.x + al.y + al.z + al.w);

    // ---- banded transition rows: t[mat][d] = sum_k ce[k]*m[mat][k][ii][ii+d-3] ----
    float t11[7], t12[7], t21[7], t22[7];
    #pragma unroll
    for (int d = 0; d < 7; ++d) {
      const int ba = ((0*7 + d)*4)*60 + ii;
      const int bb = ((1*7 + d)*4)*60 + ii;
      const int bc = ((2*7 + d)*4)*60 + ii;
      const int bd = ((3*7 + d)*4)*60 + ii;
      t11[d] = dot4(c0, m4_4[ba]) + dot4(c1, m4_4[ba+60]) + dot4(c2, m4_4[ba+120]) + dot4(c3, m4_4[ba+180]);
      t12[d] = dot4(c0, m4_4[bb]) + dot4(c1, m4_4[bb+60]) + dot4(c2, m4_4[bb+120]) + dot4(c3, m4_4[bb+180]);
      t21[d] = dot4(c0, m4_4[bc]) + dot4(c1, m4_4[bc+60]) + dot4(c2, m4_4[bc+120]) + dot4(c3, m4_4[bc+180]);
      t22[d] = dot4(c0, m4_4[bd]) + dot4(c1, m4_4[bd+60]) + dot4(c2, m4_4[bd+120]) + dot4(c3, m4_4[bd+180]);
    }

    // ---- banded mat-vec: prior mean + covariances for next step ----
    float nmu = ctrl_u, nml = ctrl_l;
    float ncu = tcu_r, ncl = tcl_r, ncs = 0.f;
    #pragma unroll
    for (int d = 0; d < 7; ++d) {
      const int si = (ii + d)*4 + b;      // state row (ii+d-3)+3
      const float mun  = stat[si];
      const float mln  = stat[288  + si];
      const float pcun = stat[576  + si];
      const float pcsn = stat[864  + si];
      const float pcln = stat[1152 + si];
      const float a11 = t11[d], a12 = t12[d], a21 = t21[d], a22 = t22[d];
      nmu += a11*mun + a12*mln;
      nml += a21*mun + a22*mln;
      ncu += a11*a11*pcun + 2.f*a11*a12*pcsn + a12*a12*pcln;
      ncl += a21*a21*pcun + 2.f*a21*a22*pcsn + a22*a22*pcln;
      ncs += a21*a11*pcun + (a22*a11 + a21*a12)*pcsn + a22*a12*pcln;
    }

    // ---- outputs (float32 — reference output dtype) ----
    if (valid) {
      const long ob = (long)gb*TT + t;
      const long ob120 = ob*120, ob60 = ob*60;
      o0[ob120 + ii]      = pm_u;
      o0[ob120 + 60 + ii] = pm_l;
      o1[ob60 + ii] = pcu;
      o2[ob60 + ii] = pcl;
      o3[ob60 + ii] = pcs;
      o4[ob120 + ii]      = nmu;
      o4[ob120 + 60 + ii] = nml;
      o5[ob60 + ii] = ncu;
      o6[ob60 + ii] = ncl;
      o7[ob60 + ii] = ncs;
    }

    // ---- carry ----
    mu_c = nmu; ml_c = nml; cu_c = ncu; cl_c = ncl; cs_c = ncs;
    __syncthreads();   // B3: protect stat/hbuf/parts rewrite next iter
  }
}

} // namespace

extern "C" void kernel_launch(void* const* d_in, const int* in_sizes, int n_in,
                              void* d_out, int out_size, void* d_ws, size_t ws_size,
                              hipStream_t stream) {
  (void)in_sizes; (void)n_in; (void)d_ws; (void)ws_size; (void)out_size;
  // Input order = setup_inputs() dict order (proven: round-3 size-check matched).
  const float* lob  = (const float*)d_in[0];
  const float* ovr  = (const float*)d_in[1];
  const float* actp = (const float*)d_in[2];
  const float* im   = (const float*)d_in[3];
  const float* icu  = (const float*)d_in[4];
  const float* icl  = (const float*)d_in[5];
  const float* ics  = (const float*)d_in[6];
  const float* tm11 = (const float*)d_in[7];
  const float* tm12 = (const float*)d_in[8];
  const float* tm21 = (const float*)d_in[9];
  const float* tm22 = (const float*)d_in[10];
  const float* cw   = (const float*)d_in[11];
  const float* cb   = (const float*)d_in[12];
  const float* w1   = (const float*)d_in[13];
  const float* b1   = (const float*)d_in[14];
  const float* w2   = (const float*)d_in[15];
  const float* b2   = (const float*)d_in[16];
  const float* ltc  = (const float*)d_in[17];

  acrkn<<<dim3(256), dim3(256), 0, stream>>>(
      lob, ovr, actp, im, icu, icl, ics,
      tm11, tm12, tm21, tm22, cw, cb, w1, b1, w2, b2, ltc,
      (float*)d_out);
}